// Round 1
// 334.385 us; speedup vs baseline: 1.0200x; 1.0200x over previous
//
#include <hip/hip_runtime.h>

#define BN 32768
#define IN 512
#define NE 8
#define NH 128
#define MO 256

typedef const __attribute__((address_space(1))) unsigned int gu32;
typedef __attribute__((address_space(3))) unsigned int lu32;

// async global->LDS, 16B per lane. LDS dest = wave-uniform base + lane*16,
// which our contiguous tid*16 layout satisfies.
__device__ __forceinline__ void cp16(const float* g, float* l) {
    __builtin_amdgcn_global_load_lds((gu32*)g, (lu32*)l, 16, 0, 0);
}

// ---------------- gating: logits, top-2, bucketing; fused out-init ----------
// One thread per (row, expert): 8 lanes per row, 32 rows/block.
// f64 accumulation so top-2 selection matches the f64 np reference at
// near-ties (an f32 rank flip would inject ~1e-3 absmax). wg is converted to
// f64 ONCE per block into LDS (row stride 514 doubles -> expert rows on
// distinct bank-quads; same-expert lanes broadcast), so the inner loop is
// 1 cvt + 1 f64 FMA per k instead of the old 9 converts + wave reduction.
__global__ __launch_bounds__(256) void gate_kernel(
    const float* __restrict__ x, const float* __restrict__ wg,
    int* __restrict__ gcount, int* __restrict__ gload, float* __restrict__ gimp,
    int* __restrict__ idx_list, float* __restrict__ gate_list,
    float* __restrict__ out, const float* __restrict__ bout)
{
    __shared__ double wgt[NE][514];   // 514 pad: row stride 4112B -> banks 4e..4e+3
    __shared__ int counts_s[NE];
    __shared__ int load_s[NE];
    __shared__ float imp_s[NE];
    __shared__ int base_s[NE];
    __shared__ int rec_e[64];
    __shared__ int rec_p[64];
    __shared__ float rec_g[64];

    int tid = threadIdx.x;
    if (tid < NE) { counts_s[tid] = 0; load_s[tid] = 0; imp_s[tid] = 0.f; }
    if (tid < 64) {  // fused init: out[row, j] = bout[j]
        int row = blockIdx.x * 32 + (tid >> 1);
        out[row * 2 + (tid & 1)] = bout[tid & 1];
    }
    // one-time convert of wg[512][8] -> wgt[e][k] (coalesced global reads)
    for (int i = tid; i < IN * NE; i += 256) {
        wgt[i & 7][i >> 3] = (double)wg[i];
    }
    __syncthreads();

    int r = tid >> 3;        // row within block, 0..31
    int e = tid & 7;         // this thread's expert
    int row = blockIdx.x * 32 + r;

    // full 512-element dot in registers; 4 independent f64 chains for ILP
    const float4* x4 = (const float4*)(x + (size_t)row * IN);
    const double* wrow = &wgt[e][0];
    double a0 = 0.0, a1 = 0.0, a2 = 0.0, a3 = 0.0;
    #pragma unroll 8
    for (int j = 0; j < 128; ++j) {
        float4 xv = x4[j];                       // 8 lanes/row broadcast-merged
        const double2* wd = (const double2*)(wrow + 4 * j);
        double2 w0 = wd[0];
        double2 w1 = wd[1];
        a0 = fma((double)xv.x, w0.x, a0);
        a1 = fma((double)xv.y, w0.y, a1);
        a2 = fma((double)xv.z, w1.x, a2);
        a3 = fma((double)xv.w, w1.y, a3);
    }
    double acc = (a0 + a1) + (a2 + a3);

    // ---- top-2 over the 8-lane expert group: 3-stage argmax butterfly ----
    // tie-break: lower expert index (matches lax.top_k)
    double v0 = acc; int e0 = e;
    #pragma unroll
    for (int m = 1; m < 8; m <<= 1) {
        double vo = __shfl_xor(v0, m, 64);
        int    eo = __shfl_xor(e0, m, 64);
        if (vo > v0 || (vo == v0 && eo < e0)) { v0 = vo; e0 = eo; }
    }
    double v1 = (e == e0) ? -1.0e300 : acc; int e1 = e;
    #pragma unroll
    for (int m = 1; m < 8; m <<= 1) {
        double vo = __shfl_xor(v1, m, 64);
        int    eo = __shfl_xor(e1, m, 64);
        if (vo > v1 || (vo == v1 && eo < e1)) { v1 = vo; e1 = eo; }
    }

    // ---- per-row bookkeeping: 8 parallel leaders per wave ----
    if ((tid & 7) == 0) {
        float t1 = expf((float)(v1 - v0));
        float s = 1.f + t1;
        float g0 = 1.f / s;
        float g1 = t1 / s;
        atomicAdd(&imp_s[e0], g0);
        atomicAdd(&imp_s[e1], g1);
        if (g0 > 0.f) atomicAdd(&load_s[e0], 1);
        if (g1 > 0.f) atomicAdd(&load_s[e1], 1);
        int p0 = atomicAdd(&counts_s[e0], 1);
        int p1 = atomicAdd(&counts_s[e1], 1);
        int rl = r * 2;
        rec_e[rl] = e0; rec_e[rl + 1] = e1;
        rec_g[rl] = g0; rec_g[rl + 1] = g1;
        rec_p[rl] = p0; rec_p[rl + 1] = p1;
    }
    __syncthreads();
    if (tid < NE) {
        base_s[tid] = atomicAdd(&gcount[tid], counts_s[tid]);
        atomicAdd(&gimp[tid], imp_s[tid]);
        atomicAdd(&gload[tid], load_s[tid]);
    }
    __syncthreads();
    if (tid < 64) {
        int ee = rec_e[tid];
        int pos = base_s[ee] + rec_p[tid];
        int rw = blockIdx.x * 32 + (tid >> 1);
        idx_list[ee * BN + pos] = rw;
        gate_list[ee * BN + pos] = rec_g[tid];
    }
}

// ---------------- loss ----------------
__global__ void loss_kernel(const float* __restrict__ gimp, const int* __restrict__ gload,
                            float* __restrict__ out) {
    if (threadIdx.x == 0 && blockIdx.x == 0) {
        float mi = 0.f, ml = 0.f;
        for (int e = 0; e < NE; ++e) { mi += gimp[e]; ml += (float)gload[e]; }
        mi *= 0.125f; ml *= 0.125f;
        float vi = 0.f, vl = 0.f;
        for (int e = 0; e < NE; ++e) {
            float d = gimp[e] - mi;  vi += d * d;
            float d2 = (float)gload[e] - ml; vl += d2 * d2;
        }
        vi *= (1.f / 7.f); vl *= (1.f / 7.f);
        float loss = (vi / (mi * mi + 1e-10f) + vl / (ml * ml + 1e-10f)) * 0.01f;
        out[BN * 2] = loss;
    }
}

// ---------------- expert compute: per (expert, 32-row tile) ----------------
// All LDS arrays row-major; A-fragments read ALONG k (b128 broadcasts), so
// no transposes, no bank conflicts. W1/W2 staged via global_load_lds (each
// chunk is a contiguous 16KB copy). LDS = exactly 32KB -> 5 blocks/CU.
__global__ __launch_bounds__(256, 5) void expert_kernel(
    const float* __restrict__ x,
    const float* __restrict__ W1, const float* __restrict__ b1,
    const float* __restrict__ W2, const float* __restrict__ b2,
    const float* __restrict__ Wout,
    const int* __restrict__ gcount,
    const int* __restrict__ idx_list, const float* __restrict__ gate_list,
    float* __restrict__ out)
{
    __shared__ __align__(16) union {
        struct { float xs[32][32]; float ws1[32][128]; } s1;  // 4K + 16K
        struct { float hs[32][128]; float w2s[16][256]; } s2; // 16K + 16K = 32K
    } sm;

    int e = blockIdx.y;
    int cnt = gcount[e];
    int row0 = blockIdx.x * 32;
    if (row0 >= cnt) return;
    int tid = threadIdx.x;
    int tx = tid & 31;   // stage1 cols tx*4; stage2 cols {tx*4, 128+tx*4}
    int ty = tid >> 5;   // rows ty*4..+3

    // this thread's gathered X row for staging (8 threads per row)
    int sr = tid >> 3, sf = tid & 7;
    int sgi = row0 + sr; if (sgi >= cnt) sgi = cnt - 1;
    const float* xrow = x + (size_t)idx_list[e * BN + sgi] * IN;

    const float* W1e = W1 + (size_t)e * IN * NH;
    const float* W2e = W2 + (size_t)e * NH * MO;

    // ---- stage 1: H[32x128] = relu(X @ W1 + b1) ----
    float c1[4][4] = {};
    for (int k0 = 0; k0 < IN; k0 += 32) {
        // xs[32][32]: lanes 0..7 write 128B contiguous per row — conflict-free
        *(float4*)&sm.s1.xs[sr][sf * 4] = *(const float4*)(xrow + k0 + sf * 4);
        // ws1: contiguous 16KB from W1[k0..k0+31][:] via async DMA
        {
            const float* g = W1e + (size_t)k0 * NH;
            float* l = &sm.s1.ws1[0][0];
            #pragma unroll
            for (int p = 0; p < 4; ++p)
                cp16(g + p * 1024 + tid * 4, l + p * 1024 + tid * 4);
        }
        __syncthreads();
        #pragma unroll
        for (int q4 = 0; q4 < 8; ++q4) {
            float a[4][4], b[4][4];
            #pragma unroll
            for (int i = 0; i < 4; ++i) {
                float4 av = *(const float4*)&sm.s1.xs[ty * 4 + i][q4 * 4];
                a[i][0] = av.x; a[i][1] = av.y; a[i][2] = av.z; a[i][3] = av.w;
            }
            #pragma unroll
            for (int q = 0; q < 4; ++q) {
                float4 bv = *(const float4*)&sm.s1.ws1[q4 * 4 + q][tx * 4];
                b[q][0] = bv.x; b[q][1] = bv.y; b[q][2] = bv.z; b[q][3] = bv.w;
            }
            #pragma unroll
            for (int q = 0; q < 4; ++q)
                #pragma unroll
                for (int i = 0; i < 4; ++i)
                    #pragma unroll
                    for (int j = 0; j < 4; ++j)
                        c1[i][j] = fmaf(a[i][q], b[q][j], c1[i][j]);
        }
        __syncthreads();
    }

    // relu + b1 -> hs (row-major, contiguous float4 stores — conflict-free).
    // hs aliases xs+ws1[0..23]; all stage-1 reads completed at trailing sync.
    {
        float4 bv = *(const float4*)(b1 + e * NH + tx * 4);
        float bb[4] = {bv.x, bv.y, bv.z, bv.w};
        #pragma unroll
        for (int i = 0; i < 4; ++i) {
            float4 h;
            h.x = fmaxf(c1[i][0] + bb[0], 0.f);
            h.y = fmaxf(c1[i][1] + bb[1], 0.f);
            h.z = fmaxf(c1[i][2] + bb[2], 0.f);
            h.w = fmaxf(c1[i][3] + bb[3], 0.f);
            *(float4*)&sm.s2.hs[ty * 4 + i][tx * 4] = h;
        }
    }

    // ---- stage 2: Z[32x256] = H @ W2 ----
    float z[4][8] = {};
    for (int k0 = 0; k0 < NH; k0 += 16) {
        {
            const float* g = W2e + (size_t)k0 * MO;
            float* l = &sm.s2.w2s[0][0];
            #pragma unroll
            for (int p = 0; p < 4; ++p)
                cp16(g + p * 1024 + tid * 4, l + p * 1024 + tid * 4);
        }
        __syncthreads();  // covers hs stores (first iter) + w2s DMA
        #pragma unroll
        for (int q4 = 0; q4 < 4; ++q4) {
            float a[4][4];
            #pragma unroll
            for (int i = 0; i < 4; ++i) {
                float4 av = *(const float4*)&sm.s2.hs[ty * 4 + i][k0 + q4 * 4];
                a[i][0] = av.x; a[i][1] = av.y; a[i][2] = av.z; a[i][3] = av.w;
            }
            #pragma unroll
            for (int q = 0; q < 4; ++q) {
                float4 blo = *(const float4*)&sm.s2.w2s[q4 * 4 + q][tx * 4];
                float4 bhi = *(const float4*)&sm.s2.w2s[q4 * 4 + q][128 + tx * 4];
                float bl[4] = {blo.x, blo.y, blo.z, blo.w};
                float bh[4] = {bhi.x, bhi.y, bhi.z, bhi.w};
                #pragma unroll
                for (int i = 0; i < 4; ++i)
                    #pragma unroll
                    for (int j = 0; j < 4; ++j) {
                        z[i][j]     = fmaf(a[i][q], bl[j], z[i][j]);
                        z[i][j + 4] = fmaf(a[i][q], bh[j], z[i][j + 4]);
                    }
            }
        }
        __syncthreads();
    }

    // ---- epilogue: softmax over 256 cols (32 lanes x 8), fused @Wout ----
    // thread's cols: j<4 -> tx*4+j ; j>=4 -> 128+tx*4+(j-4)
    float4 b2a = *(const float4*)(b2 + e * MO + tx * 4);
    float4 b2b = *(const float4*)(b2 + e * MO + 128 + tx * 4);
    float bz[8] = {b2a.x, b2a.y, b2a.z, b2a.w, b2b.x, b2b.y, b2b.z, b2b.w};
    float4 wa0 = *(const float4*)(Wout + tx * 8);
    float4 wa1 = *(const float4*)(Wout + tx * 8 + 4);
    float4 wb0 = *(const float4*)(Wout + 256 + tx * 8);
    float4 wb1 = *(const float4*)(Wout + 256 + tx * 8 + 4);
    float wo0[8] = {wa0.x, wa0.z, wa1.x, wa1.z, wb0.x, wb0.z, wb1.x, wb1.z};
    float wo1[8] = {wa0.y, wa0.w, wa1.y, wa1.w, wb0.y, wb0.w, wb1.y, wb1.w};

    #pragma unroll
    for (int i = 0; i < 4; ++i) {
        float m = -1e30f;
        #pragma unroll
        for (int j = 0; j < 8; ++j) { z[i][j] += bz[j]; m = fmaxf(m, z[i][j]); }
        #pragma unroll
        for (int mk = 1; mk < 32; mk <<= 1) m = fmaxf(m, __shfl_xor(m, mk, 64));
        float s = 0.f, w0 = 0.f, w1 = 0.f;
        #pragma unroll
        for (int j = 0; j < 8; ++j) {
            float t = __expf(z[i][j] - m);
            s += t;
            w0 = fmaf(t, wo0[j], w0);
            w1 = fmaf(t, wo1[j], w1);
        }
        #pragma unroll
        for (int mk = 1; mk < 32; mk <<= 1) {
            s  += __shfl_xor(s,  mk, 64);
            w0 += __shfl_xor(w0, mk, 64);
            w1 += __shfl_xor(w1, mk, 64);
        }
        if (tx == 0) {
            int gi = row0 + ty * 4 + i;
            if (gi < cnt) {
                float g = gate_list[e * BN + gi];
                int brow = idx_list[e * BN + gi];
                float inv = 1.f / s;
                atomicAdd(&out[brow * 2 + 0], g * w0 * inv);
                atomicAdd(&out[brow * 2 + 1], g * w1 * inv);
            }
        }
    }
}

extern "C" void kernel_launch(void* const* d_in, const int* in_sizes, int n_in,
                              void* d_out, int out_size, void* d_ws, size_t ws_size,
                              hipStream_t stream) {
    const float* x    = (const float*)d_in[0];
    // d_in[1] = cat_prop, unused by the reference
    const float* wg   = (const float*)d_in[2];
    const float* W1   = (const float*)d_in[3];
    const float* b1   = (const float*)d_in[4];
    const float* W2   = (const float*)d_in[5];
    const float* b2   = (const float*)d_in[6];
    const float* Wout = (const float*)d_in[7];
    const float* bout = (const float*)d_in[8];
    float* out = (float*)d_out;

    char* ws = (char*)d_ws;
    int*   gcount    = (int*)(ws + 0);
    int*   gload     = (int*)(ws + 32);
    float* gimp      = (float*)(ws + 64);
    int*   idx_list  = (int*)(ws + 128);
    float* gate_list = (float*)(ws + 128 + sizeof(int) * NE * BN);

    hipMemsetAsync(ws, 0, 128, stream);
    gate_kernel<<<BN / 32, 256, 0, stream>>>(x, wg, gcount, gload, gimp,
                                             idx_list, gate_list, out, bout);
    loss_kernel<<<1, 64, 0, stream>>>(gimp, gload, out);
    dim3 eg(BN / 32, NE);
    expert_kernel<<<eg, 256, 0, stream>>>(x, W1, b1, W2, b2, Wout,
                                          gcount, idx_list, gate_list, out);
}

// Round 2
// 227.982 us; speedup vs baseline: 1.4960x; 1.4667x over previous
//
#include <hip/hip_runtime.h>

#define BN 32768
#define IN 512
#define NE 8
#define NH 128
#define MO 256

typedef const __attribute__((address_space(1))) unsigned int gu32;
typedef __attribute__((address_space(3))) unsigned int lu32;
typedef __attribute__((ext_vector_type(8))) short bf16x8;
typedef __attribute__((ext_vector_type(4))) float f32x4;

// async global->LDS, 16B per lane. LDS dest = wave-uniform base + lane*16.
__device__ __forceinline__ void cp16(const float* g, float* l) {
    __builtin_amdgcn_global_load_lds((gu32*)g, (lu32*)l, 16, 0, 0);
}

// f32 -> bf16 bits, round-to-nearest-even (matches v_cvt_pk_bf16_f32)
__device__ __forceinline__ unsigned short f2bf(float f) {
    unsigned int u = __float_as_uint(f);
    u = (u + 0x7fffu + ((u >> 16) & 1u)) >> 16;
    return (unsigned short)u;
}
__device__ __forceinline__ float bf2f(unsigned short h) {
    return __uint_as_float((unsigned int)h << 16);
}

// ---------------- gating: logits, top-2, bucketing; fused out-init ----------
// One thread per (row, expert): 8 lanes per row, 32 rows/block. f64 accumulation
// so top-2 selection matches the f64 np reference at near-ties.
__global__ __launch_bounds__(256) void gate_kernel(
    const float* __restrict__ x, const float* __restrict__ wg,
    int* __restrict__ gcount, int* __restrict__ gload, float* __restrict__ gimp,
    int* __restrict__ idx_list, float* __restrict__ gate_list,
    float* __restrict__ out, const float* __restrict__ bout)
{
    __shared__ double wgt[NE][514];
    __shared__ int counts_s[NE];
    __shared__ int load_s[NE];
    __shared__ float imp_s[NE];
    __shared__ int base_s[NE];
    __shared__ int rec_e[64];
    __shared__ int rec_p[64];
    __shared__ float rec_g[64];

    int tid = threadIdx.x;
    if (tid < NE) { counts_s[tid] = 0; load_s[tid] = 0; imp_s[tid] = 0.f; }
    if (tid < 64) {  // fused init: out[row, j] = bout[j]
        int row = blockIdx.x * 32 + (tid >> 1);
        out[row * 2 + (tid & 1)] = bout[tid & 1];
    }
    for (int i = tid; i < IN * NE; i += 256) {
        wgt[i & 7][i >> 3] = (double)wg[i];
    }
    __syncthreads();

    int r = tid >> 3;
    int e = tid & 7;
    int row = blockIdx.x * 32 + r;

    const float4* x4 = (const float4*)(x + (size_t)row * IN);
    const double* wrow = &wgt[e][0];
    double a0 = 0.0, a1 = 0.0, a2 = 0.0, a3 = 0.0;
    #pragma unroll 8
    for (int j = 0; j < 128; ++j) {
        float4 xv = x4[j];
        const double2* wd = (const double2*)(wrow + 4 * j);
        double2 w0 = wd[0];
        double2 w1 = wd[1];
        a0 = fma((double)xv.x, w0.x, a0);
        a1 = fma((double)xv.y, w0.y, a1);
        a2 = fma((double)xv.z, w1.x, a2);
        a3 = fma((double)xv.w, w1.y, a3);
    }
    double acc = (a0 + a1) + (a2 + a3);

    double v0 = acc; int e0 = e;
    #pragma unroll
    for (int m = 1; m < 8; m <<= 1) {
        double vo = __shfl_xor(v0, m, 64);
        int    eo = __shfl_xor(e0, m, 64);
        if (vo > v0 || (vo == v0 && eo < e0)) { v0 = vo; e0 = eo; }
    }
    double v1 = (e == e0) ? -1.0e300 : acc; int e1 = e;
    #pragma unroll
    for (int m = 1; m < 8; m <<= 1) {
        double vo = __shfl_xor(v1, m, 64);
        int    eo = __shfl_xor(e1, m, 64);
        if (vo > v1 || (vo == v1 && eo < e1)) { v1 = vo; e1 = eo; }
    }

    if ((tid & 7) == 0) {
        float t1 = expf((float)(v1 - v0));
        float s = 1.f + t1;
        float g0 = 1.f / s;
        float g1 = t1 / s;
        atomicAdd(&imp_s[e0], g0);
        atomicAdd(&imp_s[e1], g1);
        if (g0 > 0.f) atomicAdd(&load_s[e0], 1);
        if (g1 > 0.f) atomicAdd(&load_s[e1], 1);
        int p0 = atomicAdd(&counts_s[e0], 1);
        int p1 = atomicAdd(&counts_s[e1], 1);
        int rl = r * 2;
        rec_e[rl] = e0; rec_e[rl + 1] = e1;
        rec_g[rl] = g0; rec_g[rl + 1] = g1;
        rec_p[rl] = p0; rec_p[rl + 1] = p1;
    }
    __syncthreads();
    if (tid < NE) {
        base_s[tid] = atomicAdd(&gcount[tid], counts_s[tid]);
        atomicAdd(&gimp[tid], imp_s[tid]);
        atomicAdd(&gload[tid], load_s[tid]);
    }
    __syncthreads();
    if (tid < 64) {
        int ee = rec_e[tid];
        int pos = base_s[ee] + rec_p[tid];
        int rw = blockIdx.x * 32 + (tid >> 1);
        idx_list[ee * BN + pos] = rw;
        gate_list[ee * BN + pos] = rec_g[tid];
    }
}

// ---------------- loss ----------------
__global__ void loss_kernel(const float* __restrict__ gimp, const int* __restrict__ gload,
                            float* __restrict__ out) {
    if (threadIdx.x == 0 && blockIdx.x == 0) {
        float mi = 0.f, ml = 0.f;
        for (int e = 0; e < NE; ++e) { mi += gimp[e]; ml += (float)gload[e]; }
        mi *= 0.125f; ml *= 0.125f;
        float vi = 0.f, vl = 0.f;
        for (int e = 0; e < NE; ++e) {
            float d = gimp[e] - mi;  vi += d * d;
            float d2 = (float)gload[e] - ml; vl += d2 * d2;
        }
        vi *= (1.f / 7.f); vl *= (1.f / 7.f);
        float loss = (vi / (mi * mi + 1e-10f) + vl / (ml * ml + 1e-10f)) * 0.01f;
        out[BN * 2] = loss;
    }
}

// ---------------- weight prep: split bf16 + MFMA-fragment-order blobs -------
// Fragment order for mfma_f32_16x16x32_bf16 B-operand (ladder-verified layout:
// per lane l: col n = l&15, k = 8*(l>>4)+i contiguous):
//   lane-slot(n,k) = (n&15) + 16*((k&31)>>3), byte = (k&7)*2, frag = (kstep, nfrag)
// Blob per (e,ktile): [hi 16KB][lo 16KB]; expert stages it with global_load_lds
// and reads fragments at (base + lane*16) -> fully lane-linear, conflict-free.
__global__ __launch_bounds__(256) void prep_kernel(
    const float* __restrict__ W1, const float* __restrict__ W2,
    float* __restrict__ W1F, float* __restrict__ W2F)
{
    __shared__ __align__(16) char pb[32768];
    int t = threadIdx.x, b = blockIdx.x;
    if (b < 64) {                       // W1: e = b>>3, ktile(64 k) = b&7
        int e = b >> 3, kt = b & 7;
        const float* src = W1 + ((size_t)e * IN + kt * 64) * NH;
        #pragma unroll
        for (int p = 0; p < 8; ++p) {
            int li = p * 256 + t;                 // f32-quad index, 0..2047
            float4 q = *(const float4*)(src + li * 4);
            int kl = li >> 5, n0 = (li & 31) * 4; // 32 quads per k-row (NH=128)
            int ks = kl >> 5, g = (kl >> 3) & 3, kb = (kl & 7) * 2;
            float vv[4] = {q.x, q.y, q.z, q.w};
            #pragma unroll
            for (int j = 0; j < 4; ++j) {
                int n = n0 + j;
                int off = (((ks * 8 + (n >> 4)) * 64) + (n & 15) + 16 * g) * 16 + kb;
                unsigned short hh = f2bf(vv[j]);
                unsigned short hl = f2bf(vv[j] - bf2f(hh));
                *(unsigned short*)(pb + off) = hh;
                *(unsigned short*)(pb + 16384 + off) = hl;
            }
        }
        __syncthreads();
        float* dst = W1F + (size_t)b * 8192;
        #pragma unroll
        for (int p = 0; p < 8; ++p) {
            int li = p * 256 + t;
            *(int4*)(dst + li * 4) = *(const int4*)(pb + li * 16);
        }
    } else if (b < 96) {                // W2: e = bi>>2, ktile(32 k) = bi&3
        int bi = b - 64;
        int e = bi >> 2, kt = bi & 3;
        const float* src = W2 + ((size_t)e * NH + kt * 32) * MO;
        #pragma unroll
        for (int p = 0; p < 8; ++p) {
            int li = p * 256 + t;
            float4 q = *(const float4*)(src + li * 4);
            int kl = li >> 6, n0 = (li & 63) * 4; // 64 quads per k-row (MO=256)
            int g = kl >> 3, kb = (kl & 7) * 2;
            float vv[4] = {q.x, q.y, q.z, q.w};
            #pragma unroll
            for (int j = 0; j < 4; ++j) {
                int n = n0 + j;
                int off = ((n >> 4) * 64 + (n & 15) + 16 * g) * 16 + kb;
                unsigned short hh = f2bf(vv[j]);
                unsigned short hl = f2bf(vv[j] - bf2f(hh));
                *(unsigned short*)(pb + off) = hh;
                *(unsigned short*)(pb + 16384 + off) = hl;
            }
        }
        __syncthreads();
        float* dst = W2F + (size_t)bi * 8192;
        #pragma unroll
        for (int p = 0; p < 8; ++p) {
            int li = p * 256 + t;
            *(int4*)(dst + li * 4) = *(const int4*)(pb + li * 16);
        }
    }
}

// ---------------- expert compute: split-bf16 MFMA, 64-row tiles -------------
// 4-term split (hh+hl+lh+ll): exact (xh+xl)*(wh+wl) product in f32 accum ->
// error is only the 2^-19 pair-representation error (f32-class accuracy).
// All LDS fragment traffic is lane-linear (base + lane*16): no conflicts.
#define OFF_AH 0
#define OFF_AL 8192
#define OFF_B1 16384
#define OFF_HH 0
#define OFF_HL 16384
#define OFF_B2 32768

__global__ __launch_bounds__(256, 2) void expert_kernel(
    const float* __restrict__ x,
    const float* __restrict__ b1, const float* __restrict__ b2,
    const float* __restrict__ Wout,
    const float* __restrict__ W1F, const float* __restrict__ W2F,
    const int* __restrict__ gcount,
    const int* __restrict__ idx_list, const float* __restrict__ gate_list,
    float* __restrict__ out)
{
    __shared__ __align__(16) char smx[66560];   // stage1 48K | stage2 64K | z 65K
    __shared__ float woutS[512];

    int e = blockIdx.y;
    int cnt = gcount[e];
    int row0 = blockIdx.x * 64;
    if (row0 >= cnt) return;
    int t = threadIdx.x;
    int l = t & 63, w = t >> 6;

    woutS[t] = Wout[t];
    woutS[256 + t] = Wout[256 + t];

    // staging decomposition: thread -> (mfrag, row-low, k-group)
    int s_mf = t >> 6;
    int s_r  = t & 15;
    int s_g  = (t >> 4) & 3;
    int rloc = s_mf * 16 + s_r;
    int sgi = row0 + rloc; if (sgi >= cnt) sgi = cnt - 1;
    const float* xrow = x + (size_t)idx_list[e * BN + sgi] * IN;

    int mbase = (w & 1) * 2;   // wave's M-frags: rows (w&1)*32..+31
    int nsel  = w >> 1;        // wave's col half

    // ---- stage 1: H[64x128] = relu(X @ W1 + b1), K=512 in 8 tiles of 64 ----
    f32x4 acc1[2][4] = {};
    for (int kt = 0; kt < 8; ++kt) {
        {   // W1 fragment blob (32KB) via async DMA
            const float* gb = W1F + (size_t)(e * 8 + kt) * 8192;
            float* lb = (float*)(smx + OFF_B1);
            #pragma unroll
            for (int p = 0; p < 8; ++p)
                cp16(gb + (p * 256 + t) * 4, lb + (p * 256 + t) * 4);
        }
        // x -> split-bf16 A-fragments (lane-linear b128 writes)
        #pragma unroll
        for (int ks = 0; ks < 2; ++ks) {
            int k = kt * 64 + ks * 32 + s_g * 8;
            float4 qa = *(const float4*)(xrow + k);
            float4 qb = *(const float4*)(xrow + k + 4);
            float vv[8] = {qa.x, qa.y, qa.z, qa.w, qb.x, qb.y, qb.z, qb.w};
            unsigned int dh[4], dl[4];
            #pragma unroll
            for (int j = 0; j < 4; ++j) {
                unsigned short h0 = f2bf(vv[2 * j]);
                unsigned short h1 = f2bf(vv[2 * j + 1]);
                unsigned short l0 = f2bf(vv[2 * j] - bf2f(h0));
                unsigned short l1 = f2bf(vv[2 * j + 1] - bf2f(h1));
                dh[j] = (unsigned int)h0 | ((unsigned int)h1 << 16);
                dl[j] = (unsigned int)l0 | ((unsigned int)l1 << 16);
            }
            int slot = ((ks * 4 + s_mf) * 64 + (s_r + 16 * s_g)) * 16;
            *(int4*)(smx + OFF_AH + slot) = make_int4(dh[0], dh[1], dh[2], dh[3]);
            *(int4*)(smx + OFF_AL + slot) = make_int4(dl[0], dl[1], dl[2], dl[3]);
        }
        __syncthreads();
        #pragma unroll
        for (int ks = 0; ks < 2; ++ks) {
            bf16x8 ah[2], al[2];
            #pragma unroll
            for (int mf = 0; mf < 2; ++mf) {
                int ao = ((ks * 4 + mbase + mf) * 64 + l) * 16;
                ah[mf] = *(const bf16x8*)(smx + OFF_AH + ao);
                al[mf] = *(const bf16x8*)(smx + OFF_AL + ao);
            }
            #pragma unroll
            for (int nf = 0; nf < 4; ++nf) {
                int bo = ((ks * 8 + nsel * 4 + nf) * 64 + l) * 16;
                bf16x8 bh = *(const bf16x8*)(smx + OFF_B1 + bo);
                bf16x8 bl = *(const bf16x8*)(smx + OFF_B1 + 16384 + bo);
                #pragma unroll
                for (int mf = 0; mf < 2; ++mf) {
                    acc1[mf][nf] = __builtin_amdgcn_mfma_f32_16x16x32_bf16(ah[mf], bh, acc1[mf][nf], 0, 0, 0);
                    acc1[mf][nf] = __builtin_amdgcn_mfma_f32_16x16x32_bf16(ah[mf], bl, acc1[mf][nf], 0, 0, 0);
                    acc1[mf][nf] = __builtin_amdgcn_mfma_f32_16x16x32_bf16(al[mf], bh, acc1[mf][nf], 0, 0, 0);
                    acc1[mf][nf] = __builtin_amdgcn_mfma_f32_16x16x32_bf16(al[mf], bl, acc1[mf][nf], 0, 0, 0);
                }
            }
        }
        __syncthreads();
    }

    // ---- relu(+b1), split, write H as stage-2 A-fragments ----
    #pragma unroll
    for (int mf = 0; mf < 2; ++mf) {
        int mf2 = (w & 1) * 2 + mf;
        int rlow = 4 * (l >> 4);
        #pragma unroll
        for (int nf = 0; nf < 4; ++nf) {
            int c = nsel * 64 + nf * 16 + (l & 15);
            float b1v = b1[e * NH + c];
            int ks2 = c >> 5;
            int g2 = (c >> 3) & 3;
            int boff = ((ks2 * 4 + mf2) * 64) * 16 + (c & 7) * 2;
            #pragma unroll
            for (int rg = 0; rg < 4; ++rg) {
                float v = fmaxf(acc1[mf][nf][rg] + b1v, 0.f);
                unsigned short hh = f2bf(v);
                unsigned short hl = f2bf(v - bf2f(hh));
                int off = boff + ((rlow + rg) + 16 * g2) * 16;
                *(unsigned short*)(smx + OFF_HH + off) = hh;
                *(unsigned short*)(smx + OFF_HL + off) = hl;
            }
        }
    }
    __syncthreads();

    // ---- stage 2: Z[64x256] = H @ W2, K=128 in 4 tiles of 32 ----
    f32x4 acc2[2][8] = {};
    for (int kt2 = 0; kt2 < 4; ++kt2) {
        {
            const float* gb = W2F + (size_t)(e * 4 + kt2) * 8192;
            float* lb = (float*)(smx + OFF_B2);
            #pragma unroll
            for (int p = 0; p < 8; ++p)
                cp16(gb + (p * 256 + t) * 4, lb + (p * 256 + t) * 4);
        }
        __syncthreads();
        bf16x8 ah[2], al[2];
        #pragma unroll
        for (int mf = 0; mf < 2; ++mf) {
            int ao = ((kt2 * 4 + mbase + mf) * 64 + l) * 16;
            ah[mf] = *(const bf16x8*)(smx + OFF_HH + ao);
            al[mf] = *(const bf16x8*)(smx + OFF_HL + ao);
        }
        #pragma unroll
        for (int nf = 0; nf < 8; ++nf) {
            int bo = ((nsel * 8 + nf) * 64 + l) * 16;
            bf16x8 bh = *(const bf16x8*)(smx + OFF_B2 + bo);
            bf16x8 bl = *(const bf16x8*)(smx + OFF_B2 + 16384 + bo);
            #pragma unroll
            for (int mf = 0; mf < 2; ++mf) {
                acc2[mf][nf] = __builtin_amdgcn_mfma_f32_16x16x32_bf16(ah[mf], bh, acc2[mf][nf], 0, 0, 0);
                acc2[mf][nf] = __builtin_amdgcn_mfma_f32_16x16x32_bf16(ah[mf], bl, acc2[mf][nf], 0, 0, 0);
                acc2[mf][nf] = __builtin_amdgcn_mfma_f32_16x16x32_bf16(al[mf], bh, acc2[mf][nf], 0, 0, 0);
                acc2[mf][nf] = __builtin_amdgcn_mfma_f32_16x16x32_bf16(al[mf], bl, acc2[mf][nf], 0, 0, 0);
            }
        }
        __syncthreads();
    }

    // ---- epilogue: z(+b2) -> LDS, row softmax fused with @Wout ----
    float* zl = (float*)smx;
    #pragma unroll
    for (int mf = 0; mf < 2; ++mf) {
        int rbase = (w & 1) * 32 + mf * 16 + 4 * (l >> 4);
        #pragma unroll
        for (int nf = 0; nf < 8; ++nf) {
            int c = nsel * 128 + nf * 16 + (l & 15);
            float b2v = b2[e * MO + c];
            #pragma unroll
            for (int rg = 0; rg < 4; ++rg)
                zl[(rbase + rg) * 260 + c] = acc2[mf][nf][rg] + b2v;
        }
    }
    __syncthreads();

    // 4 lanes per row, interleaved cols (c0 + 4j) -> distinct banks
    int rr = w * 16 + (l >> 2);
    int c0 = l & 3;
    float vreg[64];
    float m = -1e30f;
    #pragma unroll
    for (int j = 0; j < 64; ++j) {
        vreg[j] = zl[rr * 260 + c0 + 4 * j];
        m = fmaxf(m, vreg[j]);
    }
    m = fmaxf(m, __shfl_xor(m, 1, 64));
    m = fmaxf(m, __shfl_xor(m, 2, 64));
    float s = 0.f, o0 = 0.f, o1 = 0.f;
    #pragma unroll
    for (int j = 0; j < 64; ++j) {
        float tt = __expf(vreg[j] - m);
        s += tt;
        float2 wv = *(const float2*)&woutS[(c0 + 4 * j) * 2];
        o0 = fmaf(tt, wv.x, o0);
        o1 = fmaf(tt, wv.y, o1);
    }
    s  += __shfl_xor(s, 1, 64);  s  += __shfl_xor(s, 2, 64);
    o0 += __shfl_xor(o0, 1, 64); o0 += __shfl_xor(o0, 2, 64);
    o1 += __shfl_xor(o1, 1, 64); o1 += __shfl_xor(o1, 2, 64);
    if (c0 == 0) {
        int gi = row0 + rr;
        if (gi < cnt) {
            float g = gate_list[e * BN + gi];
            int brow = idx_list[e * BN + gi];
            float inv = 1.f / s;
            atomicAdd(&out[brow * 2 + 0], g * o0 * inv);
            atomicAdd(&out[brow * 2 + 1], g * o1 * inv);
        }
    }
}

extern "C" void kernel_launch(void* const* d_in, const int* in_sizes, int n_in,
                              void* d_out, int out_size, void* d_ws, size_t ws_size,
                              hipStream_t stream) {
    const float* x    = (const float*)d_in[0];
    // d_in[1] = cat_prop, unused by the reference
    const float* wg   = (const float*)d_in[2];
    const float* W1   = (const float*)d_in[3];
    const float* b1   = (const float*)d_in[4];
    const float* W2   = (const float*)d_in[5];
    const float* b2   = (const float*)d_in[6];
    const float* Wout = (const float*)d_in[7];
    const float* bout = (const float*)d_in[8];
    float* out = (float*)d_out;

    char* ws = (char*)d_ws;
    int*   gcount    = (int*)(ws + 0);
    int*   gload     = (int*)(ws + 32);
    float* gimp      = (float*)(ws + 64);
    int*   idx_list  = (int*)(ws + 128);
    float* gate_list = (float*)(ws + 128 + sizeof(int) * NE * BN);
    float* W1F       = (float*)(ws + 128 + 8 * NE * BN);                // 2 MB
    float* W2F       = (float*)(ws + 128 + 8 * NE * BN + 64 * 32768);  // 1 MB

    hipMemsetAsync(ws, 0, 128, stream);
    prep_kernel<<<96, 256, 0, stream>>>(W1, W2, W1F, W2F);
    gate_kernel<<<BN / 32, 256, 0, stream>>>(x, wg, gcount, gload, gimp,
                                             idx_list, gate_list, out, bout);
    loss_kernel<<<1, 64, 0, stream>>>(gimp, gload, out);
    dim3 eg(BN / 64, NE);
    expert_kernel<<<eg, 256, 0, stream>>>(x, b1, b2, Wout, W1F, W2F,
                                          gcount, idx_list, gate_list, out);
}